// Round 10
// baseline (261.437 us; speedup 1.0000x reference)
//
#include <hip/hip_runtime.h>
#include <math.h>
#include <stdint.h>

#define B_ 4096
#define T_ 128
#define S_ 16
#define C_ 128
#define L_ 33            // 2*S+1
#define NSLOT 17         // blank + 16 targets
#define NGROUP 64        // reduction groups (16 blocks = 64 batch elems each)
#define NEGV (-1e30f)
#define LOG2E 1.4426950408889634f
#define LN2 0.6931471805599453f
#define NEGB (NEGV * LOG2E)

__device__ __forceinline__ float hexp2(float x) { return __builtin_amdgcn_exp2f(x); }
__device__ __forceinline__ float hlog2(float x) { return __builtin_amdgcn_logf(x); }

// monotonic float->uint map: a > b (float) <=> fkey(a) > fkey(b) (uint)
__device__ __forceinline__ unsigned fkey(float v) {
    unsigned u = __float_as_uint(v);
    return (u & 0x80000000u) ? ~u : (u | 0x80000000u);
}

typedef const __attribute__((address_space(1))) unsigned int* gas_t;
typedef __attribute__((address_space(3))) unsigned int* las_t;

// 4 waves/block, 1 batch element per wave. Full pred rows staged coalesced
// into a rolling 3-region LDS window (3 x 8 rows x 512B = 12 KB/wave, ->
// 3 blocks/CU). Staging is target-independent, so it's issued BEFORE the
// argmax consumes the lab loads (prologue overlap). Mean fused via
// hierarchical group counters (max 64 same-address RMWs; R6 showed 4096
// RMWs on one address costs ~210us).
__global__ __launch_bounds__(256) void ctc_fused_kernel(
        const float* __restrict__ pred,   // (B, T, C) log-probs
        const float* __restrict__ lab,    // (B, S, C)
        float* __restrict__ partial,      // ws[0..B): nll/S per element
        float* __restrict__ gsum,         // ws[B..B+64): group sums
        int* __restrict__ gcnt,           // 64 group counters (zeroed)
        int* __restrict__ fcnt,           // final counter (zeroed)
        float* __restrict__ out) {        // d_out[0]
    const int wid  = threadIdx.x >> 6;
    const int lane = threadIdx.x & 63;
    const int b = blockIdx.x * 4 + wid;
    const int g = blockIdx.x >> 4;        // group: b in [g*64, g*64+64)

    __shared__ int   cls_tab[4][NSLOT];
    __shared__ float lps[4][3 * 1024];    // 3 regions x 8 rows x 128 floats
    __shared__ int   winner_flag;
    int*   mytab = cls_tab[wid];
    float* mylds = lps[wid];

    const int half = lane >> 5;
    const int li   = lane & 31;
    const float* pb = pred + (size_t)b * T_ * C_;

    // ---- staging: chunk c = rows [8c, 8c+8) -> region (c%3), 4 instrs ----
    auto stage_chunk = [&](int c) {
        const int roff = (c % 3) * 1024;  // floats
        #pragma unroll
        for (int j = 0; j < 4; ++j) {
            int row = c * 8 + 2 * j + half;
            const float* src = pb + (size_t)row * C_ + li * 4;   // 16B/lane
            __builtin_amdgcn_global_load_lds((gas_t)src,
                                             (las_t)(mylds + roff + j * 256), 16, 0, 0);
        }
        __builtin_amdgcn_sched_barrier(0);               // pin issue order
    };

    // ---- prologue: lab loads, then 3 staging chunks, all in flight ----
    const float4* lr =
        (const float4*)(lab + (size_t)b * S_ * C_ + (size_t)half * C_);
    float4 q[8];
    #pragma unroll
    for (int sp = 0; sp < 8; ++sp)
        q[sp] = lr[(size_t)sp * 2 * (C_ / 4) + li];      // 8 indep 16B loads
    __builtin_amdgcn_sched_barrier(0);
    stage_chunk(0);                       // rows  0-7  -> region 0
    stage_chunk(1);                       // rows  8-15 -> region 1
    stage_chunk(2);                       // rows 16-23 -> region 2

    asm volatile("s_waitcnt vmcnt(12)" ::: "memory");    // lab loads done

    // ---- argmax (targets), while chunks 0-2 are in flight ----
    if (lane == 0) mytab[0] = 0;          // blank class
    #pragma unroll
    for (int sp = 0; sp < 8; ++sp) {
        float vals[4] = {q[sp].x, q[sp].y, q[sp].z, q[sp].w};
        unsigned long long key = 0;       // fkey(v)<<32 | ~idx: max == (max v, min idx)
        #pragma unroll
        for (int k = 0; k < 4; ++k) {
            unsigned long long kk =
                ((unsigned long long)fkey(vals[k]) << 32) | (unsigned)(~(li * 4 + k));
            if (kk > key) key = kk;       // strict >, k ascending: first index wins
        }
        #pragma unroll
        for (int off = 16; off >= 1; off >>= 1) {
            unsigned long long ok = __shfl_xor(key, off, 64);  // within half
            if (ok > key) key = ok;
        }
        if (li == 0) mytab[1 + sp * 2 + half] = (int)(~(unsigned)key) & 127;
    }
    asm volatile("s_waitcnt lgkmcnt(0)" ::: "memory");   // cls_tab visible in-wave

    // lane -> DP state constants
    const int l = lane;
    int cidx = 0;
    if (l < L_ && (l & 1)) cidx = 1 + ((l - 1) >> 1);
    const int  cls   = mytab[cidx];       // this lane's class id (0 for blanks)
    const bool has2  = (l >= 1);
    const bool skipv =
        (l < L_ && (l & 1) && l >= 3) && (mytab[cidx] != mytab[cidx - 1]);

    // LDS float index of row tt, this lane's class (3-region circular window)
#define LPOFF(tt) ((((tt) >> 3) % 3) * 1024 + (((tt) & 7) << 7) + cls)

    float beta, lpA, lpB, lpC;
#define SEG(T0, T1)                                                         \
    _Pragma("unroll 4")                                                     \
    for (int t = (T0); t <= (T1); ++t) {                                    \
        float lp = lpA; lpA = lpB; lpB = lpC;                               \
        lpC = mylds[LPOFF(t + 3)];                                          \
        float a2 = __shfl_up(beta, 1, 64);                                  \
        float a3 = __shfl_up(beta, 2, 64);                                  \
        a2 = has2  ? a2 : NEGB;                                             \
        a3 = skipv ? a3 : NEGB;                                             \
        float m = fmaxf(fmaxf(beta, a2), a3);                               \
        float s = hexp2(beta - m) + hexp2(a2 - m) + hexp2(a3 - m);          \
        beta = fmaf(lp, LOG2E, m + hlog2(s));                               \
    }

    asm volatile("s_waitcnt vmcnt(8)" ::: "memory");     // chunk 0 ready

    beta = (l <= 1) ? mylds[cls] * LOG2E : NEGB;         // t = 0 (row 0)
    lpA = mylds[LPOFF(1)];
    lpB = mylds[LPOFF(2)];
    lpC = mylds[LPOFF(3)];
    SEG(1, 4)                             // rows 4-7 via lpC (chunk 0)

    // steady state: consume chunk j (region j%3) while j+1, j+2 in flight;
    // stage chunk j+2 into the region chunk j-1 just vacated.
    #pragma unroll
    for (int j = 1; j <= 13; ++j) {
        stage_chunk(j + 2);               // region (j+2)%3 == (j-1)%3, vacated
        asm volatile("s_waitcnt vmcnt(8)" ::: "memory"); // chunk j ready
        SEG(8 * j - 3, 8 * j + 4)         // reads rows 8j..8j+7
    }
    asm volatile("s_waitcnt vmcnt(4)" ::: "memory");     // chunk 14 ready
    SEG(109, 116)
    asm volatile("s_waitcnt vmcnt(0)" ::: "memory");     // chunk 15 ready
    SEG(117, 124)
    SEG(125, 127)                         // rows 128-130: dead pad reads
#undef SEG
#undef LPOFF

    float b31 = __shfl(beta, L_ - 2, 64);
    float b32 = __shfl(beta, L_ - 1, 64);
    float m2 = fmaxf(b31, b32);
    float nll = -(m2 + hlog2(hexp2(b31 - m2) + hexp2(b32 - m2))) * LN2;
    if (!isfinite(nll)) nll = 0.0f;       // zero_infinity
    float val = nll * (1.0f / (float)S_);
    if (lane == 0)
        __hip_atomic_store(&partial[b], val, __ATOMIC_RELEASE,
                           __HIP_MEMORY_SCOPE_AGENT);

    // ---- fused hierarchical mean (deterministic: fixed-order sums) ----
    __syncthreads();                      // all 4 partials of this block stored
    if (threadIdx.x == 0)
        winner_flag = __hip_atomic_fetch_add(&gcnt[g], 1, __ATOMIC_ACQ_REL,
                                             __HIP_MEMORY_SCOPE_AGENT);
    __syncthreads();
    if (threadIdx.x < 64 && winner_flag == 15) {   // last block of group g
        __threadfence();
        float s = __hip_atomic_load(&partial[g * 64 + lane], __ATOMIC_RELAXED,
                                    __HIP_MEMORY_SCOPE_AGENT);
        #pragma unroll
        for (int off = 1; off < 64; off <<= 1)
            s += __shfl_xor(s, off, 64);  // fixed butterfly order
        int fold = 0;
        if (lane == 0) {
            __hip_atomic_store(&gsum[g], s, __ATOMIC_RELEASE,
                               __HIP_MEMORY_SCOPE_AGENT);
            fold = __hip_atomic_fetch_add(fcnt, 1, __ATOMIC_ACQ_REL,
                                          __HIP_MEMORY_SCOPE_AGENT);
        }
        fold = __shfl(fold, 0, 64);
        if (fold == NGROUP - 1) {         // last group winner: final mean
            __threadfence();
            float tsum = __hip_atomic_load(&gsum[lane], __ATOMIC_RELAXED,
                                           __HIP_MEMORY_SCOPE_AGENT);
            #pragma unroll
            for (int off = 1; off < 64; off <<= 1)
                tsum += __shfl_xor(tsum, off, 64);   // fixed butterfly order
            if (lane == 0) *out = tsum * (1.0f / (float)B_);
        }
    }
}

extern "C" void kernel_launch(void* const* d_in, const int* in_sizes, int n_in,
                              void* d_out, int out_size, void* d_ws, size_t ws_size,
                              hipStream_t stream) {
    const float* pred = (const float*)d_in[0];  // (B,T,C) fp32
    const float* lab  = (const float*)d_in[1];  // (B,S,C) fp32
    float* ws = (float*)d_ws;
    float* partial = ws;                        // [0, 4096)
    float* gsum    = ws + B_;                   // [4096, 4160)
    int*   gcnt    = (int*)(ws + B_ + NGROUP);  // 64 ints
    int*   fcnt    = gcnt + NGROUP;             // 1 int
    hipMemsetAsync(gcnt, 0, (NGROUP + 1) * sizeof(int), stream);  // graph-legal
    ctc_fused_kernel<<<B_ / 4, 256, 0, stream>>>(pred, lab, partial, gsum,
                                                 gcnt, fcnt, (float*)d_out);
}

// Round 11
// 56.321 us; speedup vs baseline: 4.6419x; 4.6419x over previous
//
#include <hip/hip_runtime.h>
#include <math.h>
#include <stdint.h>

#define B_ 4096
#define T_ 128
#define S_ 16
#define C_ 128
#define L_ 33            // 2*S+1
#define NSLOT 17         // blank + 16 targets
#define NEGV (-1e30f)
#define LOG2E 1.4426950408889634f
#define LN2 0.6931471805599453f
#define NEGB (NEGV * LOG2E)

__device__ __forceinline__ float hexp2(float x) { return __builtin_amdgcn_exp2f(x); }
__device__ __forceinline__ float hlog2(float x) { return __builtin_amdgcn_logf(x); }

// monotonic float->uint map: a > b (float) <=> fkey(a) > fkey(b) (uint)
__device__ __forceinline__ unsigned fkey(float v) {
    unsigned u = __float_as_uint(v);
    return (u & 0x80000000u) ? ~u : (u | 0x80000000u);
}

typedef const __attribute__((address_space(1))) unsigned int* gas_t;
typedef __attribute__((address_space(3))) unsigned int* las_t;

// R9 structure (best: 57us): 4 waves/block, 1 elem/wave, full pred rows staged
// coalesced into a rolling 2-region LDS window (2 x 8 rows x 512B = 8 KB/wave).
// R11 deltas: (1) SEG fully unrolled -> LPOFF compile-time -> ds_read with
// immediate offsets, zero per-step address VALU; (2) staging chunks 0-1 issued
// BEFORE argmax (target-independent). NO fused reduce: R5/R6/R10 all showed
// device-scope atomic/fence reduction costs ~200-280us regardless of RMW fan-in.
__global__ __launch_bounds__(256, 4) void ctc_main_kernel(
        const float* __restrict__ pred,   // (B, T, C) log-probs
        const float* __restrict__ lab,    // (B, S, C)
        float* __restrict__ out_b) {      // ws[0..B): nll/S per element
    const int wid  = threadIdx.x >> 6;
    const int lane = threadIdx.x & 63;
    const int b = blockIdx.x * 4 + wid;

    __shared__ int   cls_tab[4][NSLOT];
    __shared__ float lps[4][2048];        // 2 regions x 8 rows x 128 floats
    int*   mytab = cls_tab[wid];
    float* mylds = lps[wid];

    const int half = lane >> 5;
    const int li   = lane & 31;
    const float* pb = pred + (size_t)b * T_ * C_;

    // ---- staging: chunk c = rows [8c, 8c+8) -> region (c&1), 4 instrs ----
    auto stage_chunk = [&](int c) {
        const int roff = (c & 1) * 1024;  // floats
        #pragma unroll
        for (int j = 0; j < 4; ++j) {
            int row = c * 8 + 2 * j + half;
            const float* src = pb + (size_t)row * C_ + li * 4;   // 16B/lane
            __builtin_amdgcn_global_load_lds((gas_t)src,
                                             (las_t)(mylds + roff + j * 256), 16, 0, 0);
        }
        __builtin_amdgcn_sched_barrier(0);               // pin issue order
    };

    // ---- prologue: lab loads, then 2 staging chunks, all in flight ----
    const float4* lr =
        (const float4*)(lab + (size_t)b * S_ * C_ + (size_t)half * C_);
    float4 q[8];
    #pragma unroll
    for (int sp = 0; sp < 8; ++sp)
        q[sp] = lr[(size_t)sp * 2 * (C_ / 4) + li];      // 8 indep 16B loads
    __builtin_amdgcn_sched_barrier(0);
    stage_chunk(0);                       // rows 0-7  -> region 0
    stage_chunk(1);                       // rows 8-15 -> region 1

    asm volatile("s_waitcnt vmcnt(8)" ::: "memory");     // lab loads done

    // ---- argmax (targets) while chunks 0-1 are in flight ----
    if (lane == 0) mytab[0] = 0;          // blank class
    #pragma unroll
    for (int sp = 0; sp < 8; ++sp) {
        float vals[4] = {q[sp].x, q[sp].y, q[sp].z, q[sp].w};
        unsigned long long key = 0;       // fkey(v)<<32 | ~idx: max == (max v, min idx)
        #pragma unroll
        for (int k = 0; k < 4; ++k) {
            unsigned long long kk =
                ((unsigned long long)fkey(vals[k]) << 32) | (unsigned)(~(li * 4 + k));
            if (kk > key) key = kk;       // strict >, k ascending: first index wins
        }
        #pragma unroll
        for (int off = 16; off >= 1; off >>= 1) {
            unsigned long long ok = __shfl_xor(key, off, 64);  // within half
            if (ok > key) key = ok;
        }
        if (li == 0) mytab[1 + sp * 2 + half] = (int)(~(unsigned)key) & 127;
    }
    asm volatile("s_waitcnt lgkmcnt(0)" ::: "memory");   // cls_tab visible in-wave

    // lane -> DP state constants
    const int l = lane;
    int cidx = 0;
    if (l < L_ && (l & 1)) cidx = 1 + ((l - 1) >> 1);
    const int  cls   = mytab[cidx];       // this lane's class id (0 for blanks)
    const bool has2  = (l >= 1);
    const bool skipv =
        (l < L_ && (l & 1) && l >= 3) && (mytab[cidx] != mytab[cidx - 1]);

    // LDS float index of row tt for this lane (2-region circular window).
    // All uses below have compile-time tt -> folds to ds_read immediate offset.
#define LPOFF(tt) (((((tt) >> 3) & 1) << 10) + ((((tt) >> 1) & 3) << 8) \
                   + (((tt) & 1) << 7) + cls)

    float beta, lpA, lpB, lpC;
#define SEG(T0, T1)                                                         \
    _Pragma("unroll")                                                       \
    for (int t = (T0); t <= (T1); ++t) {                                    \
        float lp = lpA; lpA = lpB; lpB = lpC;                               \
        lpC = mylds[LPOFF(t + 3)];                                          \
        float a2 = __shfl_up(beta, 1, 64);                                  \
        float a3 = __shfl_up(beta, 2, 64);                                  \
        a2 = has2  ? a2 : NEGB;                                             \
        a3 = skipv ? a3 : NEGB;                                             \
        float m = fmaxf(fmaxf(beta, a2), a3);                               \
        float s = hexp2(beta - m) + hexp2(a2 - m) + hexp2(a3 - m);          \
        beta = fmaf(lp, LOG2E, m + hlog2(s));                               \
    }

    asm volatile("s_waitcnt vmcnt(4)" ::: "memory");     // chunk 0 ready

    beta = (l <= 1) ? mylds[cls] * LOG2E : NEGB;         // t = 0 (row 0)
    lpA = mylds[LPOFF(1)];
    lpB = mylds[LPOFF(2)];
    lpC = mylds[LPOFF(3)];

    SEG(1, 4)                             // prefetch rows 4-7 (chunk 0)
    #pragma unroll
    for (int c = 2; c <= 15; ++c) {
        stage_chunk(c);                   // rows 8c..8c+7 -> region (c&1)
        asm volatile("s_waitcnt vmcnt(4)" ::: "memory"); // chunk c-1 ready
        SEG(8 * c - 11, 8 * c - 4)        // prefetch rows 8c-8 .. 8c-1
    }
    asm volatile("s_waitcnt vmcnt(0)" ::: "memory");     // chunk 15 ready
    SEG(117, 127)                         // prefetch rows 120-130 (128-130 dead)
#undef SEG
#undef LPOFF

    float b31 = __shfl(beta, L_ - 2, 64);
    float b32 = __shfl(beta, L_ - 1, 64);
    float m2 = fmaxf(b31, b32);
    float nll = -(m2 + hlog2(hexp2(b31 - m2) + hexp2(b32 - m2))) * LN2;
    if (!isfinite(nll)) nll = 0.0f;       // zero_infinity
    if (lane == 0) out_b[b] = nll * (1.0f / (float)S_);
}

__global__ __launch_bounds__(256) void reduce_mean_kernel(
        const float* __restrict__ in, float* __restrict__ out) {
    __shared__ float sm[256];
    const int tid = threadIdx.x;
    float v[16];
    #pragma unroll
    for (int i = 0; i < 16; ++i) v[i] = in[tid + i * 256];
    float s = 0.f;
    #pragma unroll
    for (int i = 0; i < 16; ++i) s += v[i];
    sm[tid] = s;
    __syncthreads();
    for (int w = 128; w >= 1; w >>= 1) {
        if (tid < w) sm[tid] += sm[tid + w];
        __syncthreads();
    }
    if (tid == 0) out[0] = sm[0] / (float)B_;
}

extern "C" void kernel_launch(void* const* d_in, const int* in_sizes, int n_in,
                              void* d_out, int out_size, void* d_ws, size_t ws_size,
                              hipStream_t stream) {
    const float* pred = (const float*)d_in[0];  // (B,T,C) fp32
    const float* lab  = (const float*)d_in[1];  // (B,S,C) fp32
    float* ws = (float*)d_ws;                   // B partial losses
    ctc_main_kernel<<<B_ / 4, 256, 0, stream>>>(pred, lab, ws);
    reduce_mean_kernel<<<1, 256, 0, stream>>>(ws, (float*)d_out);
}

// Round 12
// 56.078 us; speedup vs baseline: 4.6620x; 1.0043x over previous
//
#include <hip/hip_runtime.h>
#include <math.h>
#include <stdint.h>

#define B_ 4096
#define T_ 128
#define S_ 16
#define C_ 128
#define L_ 33            // 2*S+1
#define NSLOT 17         // blank + 16 targets
#define NEGV (-1e30f)
#define LOG2E 1.4426950408889634f
#define LN2 0.6931471805599453f
#define NEGB (NEGV * LOG2E)

__device__ __forceinline__ float hexp2(float x) { return __builtin_amdgcn_exp2f(x); }
__device__ __forceinline__ float hlog2(float x) { return __builtin_amdgcn_logf(x); }

// monotonic float->uint map: a > b (float) <=> fkey(a) > fkey(b) (uint)
__device__ __forceinline__ unsigned fkey(float v) {
    unsigned u = __float_as_uint(v);
    return (u & 0x80000000u) ? ~u : (u | 0x80000000u);
}

typedef const __attribute__((address_space(1))) unsigned int* gas_t;
typedef __attribute__((address_space(3))) unsigned int* las_t;

// R11 structure (56.3us) + touched-line masking: the 17 classes of a batch
// element hit on avg 7.2 of the 8 64B-lines per pred row; lanes covering
// untouched lines are exec-masked out of staging (chunks 2-15), cutting ~9%
// of CU-side bytes. Line 0 (blank) is always touched -> exec never 0 ->
// all 4 loads/chunk always issue -> counted vmcnt stays valid. LDS holes
// are never read (cls addresses touched lines only).
__global__ __launch_bounds__(256, 4) void ctc_main_kernel(
        const float* __restrict__ pred,   // (B, T, C) log-probs
        const float* __restrict__ lab,    // (B, S, C)
        float* __restrict__ out_b) {      // ws[0..B): nll/S per element
    const int wid  = threadIdx.x >> 6;
    const int lane = threadIdx.x & 63;
    const int b = blockIdx.x * 4 + wid;

    __shared__ int   cls_tab[4][NSLOT];
    __shared__ float lps[4][2048];        // 2 regions x 8 rows x 128 floats
    int*   mytab = cls_tab[wid];
    float* mylds = lps[wid];

    const int half = lane >> 5;
    const int li   = lane & 31;
    const float* pb = pred + (size_t)b * T_ * C_;

    // ---- staging: chunk c = rows [8c, 8c+8) -> region (c&1), 4 instrs ----
    auto stage_chunk = [&](int c) {       // unmasked (prologue, pre-argmax)
        const int roff = (c & 1) * 1024;  // floats
        #pragma unroll
        for (int j = 0; j < 4; ++j) {
            int row = c * 8 + 2 * j + half;
            const float* src = pb + (size_t)row * C_ + li * 4;   // 16B/lane
            __builtin_amdgcn_global_load_lds((gas_t)src,
                                             (las_t)(mylds + roff + j * 256), 16, 0, 0);
        }
        __builtin_amdgcn_sched_barrier(0);               // pin issue order
    };

    // ---- prologue: lab loads, then 2 staging chunks, all in flight ----
    const float4* lr =
        (const float4*)(lab + (size_t)b * S_ * C_ + (size_t)half * C_);
    float4 q[8];
    #pragma unroll
    for (int sp = 0; sp < 8; ++sp)
        q[sp] = lr[(size_t)sp * 2 * (C_ / 4) + li];      // 8 indep 16B loads
    __builtin_amdgcn_sched_barrier(0);
    stage_chunk(0);                       // rows 0-7  -> region 0
    stage_chunk(1);                       // rows 8-15 -> region 1

    asm volatile("s_waitcnt vmcnt(8)" ::: "memory");     // lab loads done

    // ---- argmax (targets) while chunks 0-1 are in flight ----
    if (lane == 0) mytab[0] = 0;          // blank class
    #pragma unroll
    for (int sp = 0; sp < 8; ++sp) {
        float vals[4] = {q[sp].x, q[sp].y, q[sp].z, q[sp].w};
        unsigned long long key = 0;       // fkey(v)<<32 | ~idx: max == (max v, min idx)
        #pragma unroll
        for (int k = 0; k < 4; ++k) {
            unsigned long long kk =
                ((unsigned long long)fkey(vals[k]) << 32) | (unsigned)(~(li * 4 + k));
            if (kk > key) key = kk;       // strict >, k ascending: first index wins
        }
        #pragma unroll
        for (int off = 16; off >= 1; off >>= 1) {
            unsigned long long ok = __shfl_xor(key, off, 64);  // within half
            if (ok > key) key = ok;
        }
        if (li == 0) mytab[1 + sp * 2 + half] = (int)(~(unsigned)key) & 127;
    }
    asm volatile("s_waitcnt lgkmcnt(0)" ::: "memory");   // cls_tab visible in-wave

    // lane -> DP state constants
    const int l = lane;
    int cidx = 0;
    if (l < L_ && (l & 1)) cidx = 1 + ((l - 1) >> 1);
    const int  cls   = mytab[cidx];       // this lane's class id (0 for blanks)
    const bool has2  = (l >= 1);
    const bool skipv =
        (l < L_ && (l & 1) && l >= 3) && (mytab[cidx] != mytab[cidx - 1]);

    // ---- touched-line mask: which of the 8 64B-lines per row are needed ----
    unsigned lm = (lane < NSLOT) ? (1u << (mytab[lane] >> 4)) : 0u;
    #pragma unroll
    for (int off = 1; off < 64; off <<= 1) lm |= __shfl_xor(lm, off, 64);
    const bool myline = (lm >> (li >> 2)) & 1;   // this lane's 16B covers line li>>2

    auto stage_chunk_m = [&](int c) {     // masked: skip untouched lines
        const int roff = (c & 1) * 1024;  // floats
        #pragma unroll
        for (int j = 0; j < 4; ++j) {
            int row = c * 8 + 2 * j + half;
            const float* src = pb + (size_t)row * C_ + li * 4;   // 16B/lane
            if (myline)                   // exec-mask; lanes 0-3 always on
                __builtin_amdgcn_global_load_lds((gas_t)src,
                                                 (las_t)(mylds + roff + j * 256), 16, 0, 0);
        }
        __builtin_amdgcn_sched_barrier(0);               // pin issue order
    };

    // LDS float index of row tt for this lane (2-region circular window).
    // All uses below have compile-time tt -> folds to ds_read immediate offset.
#define LPOFF(tt) (((((tt) >> 3) & 1) << 10) + ((((tt) >> 1) & 3) << 8) \
                   + (((tt) & 1) << 7) + cls)

    float beta, lpA, lpB, lpC;
#define SEG(T0, T1)                                                         \
    _Pragma("unroll")                                                       \
    for (int t = (T0); t <= (T1); ++t) {                                    \
        float lp = lpA; lpA = lpB; lpB = lpC;                               \
        lpC = mylds[LPOFF(t + 3)];                                          \
        float a2 = __shfl_up(beta, 1, 64);                                  \
        float a3 = __shfl_up(beta, 2, 64);                                  \
        a2 = has2  ? a2 : NEGB;                                             \
        a3 = skipv ? a3 : NEGB;                                             \
        float m = fmaxf(fmaxf(beta, a2), a3);                               \
        float s = hexp2(beta - m) + hexp2(a2 - m) + hexp2(a3 - m);          \
        beta = fmaf(lp, LOG2E, m + hlog2(s));                               \
    }

    asm volatile("s_waitcnt vmcnt(4)" ::: "memory");     // chunk 0 ready

    beta = (l <= 1) ? mylds[cls] * LOG2E : NEGB;         // t = 0 (row 0)
    lpA = mylds[LPOFF(1)];
    lpB = mylds[LPOFF(2)];
    lpC = mylds[LPOFF(3)];

    SEG(1, 4)                             // prefetch rows 4-7 (chunk 0)
    #pragma unroll
    for (int c = 2; c <= 15; ++c) {
        stage_chunk_m(c);                 // rows 8c..8c+7 -> region (c&1)
        asm volatile("s_waitcnt vmcnt(4)" ::: "memory"); // chunk c-1 ready
        SEG(8 * c - 11, 8 * c - 4)        // prefetch rows 8c-8 .. 8c-1
    }
    asm volatile("s_waitcnt vmcnt(0)" ::: "memory");     // chunk 15 ready
    SEG(117, 127)                         // prefetch rows 120-130 (128-130 dead)
#undef SEG
#undef LPOFF

    float b31 = __shfl(beta, L_ - 2, 64);
    float b32 = __shfl(beta, L_ - 1, 64);
    float m2 = fmaxf(b31, b32);
    float nll = -(m2 + hlog2(hexp2(b31 - m2) + hexp2(b32 - m2))) * LN2;
    if (!isfinite(nll)) nll = 0.0f;       // zero_infinity
    if (lane == 0) out_b[b] = nll * (1.0f / (float)S_);
}

__global__ __launch_bounds__(256) void reduce_mean_kernel(
        const float* __restrict__ in, float* __restrict__ out) {
    __shared__ float sm[256];
    const int tid = threadIdx.x;
    float v[16];
    #pragma unroll
    for (int i = 0; i < 16; ++i) v[i] = in[tid + i * 256];
    float s = 0.f;
    #pragma unroll
    for (int i = 0; i < 16; ++i) s += v[i];
    sm[tid] = s;
    __syncthreads();
    for (int w = 128; w >= 1; w >>= 1) {
        if (tid < w) sm[tid] += sm[tid + w];
        __syncthreads();
    }
    if (tid == 0) out[0] = sm[0] / (float)B_;
}

extern "C" void kernel_launch(void* const* d_in, const int* in_sizes, int n_in,
                              void* d_out, int out_size, void* d_ws, size_t ws_size,
                              hipStream_t stream) {
    const float* pred = (const float*)d_in[0];  // (B,T,C) fp32
    const float* lab  = (const float*)d_in[1];  // (B,S,C) fp32
    float* ws = (float*)d_ws;                   // B partial losses
    ctc_main_kernel<<<B_ / 4, 256, 0, stream>>>(pred, lab, ws);
    reduce_mean_kernel<<<1, 256, 0, stream>>>(ws, (float*)d_out);
}